// Round 1
// baseline (565.629 us; speedup 1.0000x reference)
//
#include <hip/hip_runtime.h>

#define HDIM 256
#define WDIM 704
#define HW (HDIM * WDIM)
#define CIMG 256
#define COUT 131

// ---------------------------------------------------------------------------
// Precompute tiny fused matrices (all linear algebra pushed through rd2 + sp):
//   T[k][c]  = sum_j sp_w[j,k] * rd2_w[j,c]            (9 x 131)  == G2
//   G0[k][i] = sum_c T[k][c] * rd0_w[c,i]              (9 x 35)
//   G1[k][i] = sum_c T[k][c] * rd1_w[c,i]              (9 x 67)
//   base2[j] = rd2_b[j] + sum_c rd2_w[j,c]*(rd0_b[c]+rd1_b[c])
//   cb[k]    = sum_j sp_w[j,k] * base2[j]              (bias constant per tap)
//   wg[k]    = sum_j sp_w[j,k]                         (gated broadcast weight)
// ---------------------------------------------------------------------------
__global__ void precompute_kernel(const float* __restrict__ rd0_w, const float* __restrict__ rd0_b,
                                  const float* __restrict__ rd1_w, const float* __restrict__ rd1_b,
                                  const float* __restrict__ rd2_w, const float* __restrict__ rd2_b,
                                  const float* __restrict__ sp_w,
                                  float* __restrict__ T, float* __restrict__ G0,
                                  float* __restrict__ G1, float* __restrict__ cbwg) {
    __shared__ float s_base2[COUT];
    __shared__ float s_T[9 * COUT];
    int t = threadIdx.x;
    for (int j = t; j < COUT; j += blockDim.x) {
        float acc = rd2_b[j];
        for (int c = 0; c < COUT; ++c) acc += rd2_w[j * COUT + c] * (rd0_b[c] + rd1_b[c]);
        s_base2[j] = acc;
    }
    for (int e = t; e < 9 * COUT; e += blockDim.x) {
        int k = e / COUT, c = e - k * COUT;
        float acc = 0.f;
        for (int j = 0; j < COUT; ++j) acc += sp_w[j * 9 + k] * rd2_w[j * COUT + c];
        s_T[e] = acc;
        T[e] = acc;
    }
    __syncthreads();
    for (int e = t; e < 9 * 35; e += blockDim.x) {
        int k = e / 35, i = e - k * 35;
        float acc = 0.f;
        for (int c = 0; c < COUT; ++c) acc += s_T[k * COUT + c] * rd0_w[c * 35 + i];
        G0[e] = acc;
    }
    for (int e = t; e < 9 * 67; e += blockDim.x) {
        int k = e / 67, i = e - k * 67;
        float acc = 0.f;
        for (int c = 0; c < COUT; ++c) acc += s_T[k * COUT + c] * rd1_w[c * 67 + i];
        G1[e] = acc;
    }
    if (t < 9) {
        float acc = 0.f, accw = 0.f;
        for (int j = 0; j < COUT; ++j) {
            acc += sp_w[j * 9 + t] * s_base2[j];
            accw += sp_w[j * 9 + t];
        }
        cbwg[t] = acc;
        cbwg[9 + t] = accw;
    }
}

// gated(h,w) = rd3_b + sum_c rd3_w[c] * img[c,h,w]
__global__ void gated_kernel(const float* __restrict__ img, const float* __restrict__ rd3_w,
                             const float* __restrict__ rd3_b, float* __restrict__ gated) {
    int pix = blockIdx.x * blockDim.x + threadIdx.x;
    if (pix >= HW) return;
    float g = rd3_b[0];
#pragma unroll 8
    for (int c = 0; c < CIMG; ++c) g += rd3_w[c] * img[(size_t)c * HW + pix];
    gated[pix] = g;
}

// Per point: t[k] = G[k,:] . [feat;coord], scatter t[k] into logit image L at
// pixel (row - (kh-1), col - (kw-1)).  16 lanes per point for coalesced loads.
__global__ void scatter_kernel(const float* __restrict__ feat, const float* __restrict__ coord,
                               const int* __restrict__ grid, const float* __restrict__ G,
                               float* __restrict__ L, int n, int C) {
    int gid = blockIdx.x * blockDim.x + threadIdx.x;
    int p = gid >> 4;
    int lane = gid & 15;
    if (p >= n) return;
    int D = C + 3;
    float part[9];
#pragma unroll
    for (int k = 0; k < 9; ++k) part[k] = 0.f;
    for (int i = lane; i < D; i += 16) {
        float x = (i < C) ? feat[(size_t)p * C + i] : coord[(size_t)p * 3 + (i - C)];
#pragma unroll
        for (int k = 0; k < 9; ++k) part[k] += G[k * D + i] * x;
    }
#pragma unroll
    for (int k = 0; k < 9; ++k) {
        float v = part[k];
        v += __shfl_xor(v, 1);
        v += __shfl_xor(v, 2);
        v += __shfl_xor(v, 4);
        v += __shfl_xor(v, 8);
        part[k] = v;
    }
    if (lane < 9) {
        int kh = lane / 3, kw = lane - kh * 3;
        int cx = grid[2 * p], cy = grid[2 * p + 1];
        int h = cy - (kh - 1), w = cx - (kw - 1);
        if (h >= 0 && h < HDIM && w >= 0 && w < WDIM)
            atomicAdd(&L[h * WDIM + w], part[lane]);
    }
}

// logit = sp_b + L + sum over valid taps (cb[k] + wg[k]*gated[neighbor]); att = sigmoid
__global__ void attention_kernel(const float* __restrict__ gated, const float* __restrict__ L,
                                 const float* __restrict__ cbwg, const float* __restrict__ sp_b,
                                 float* __restrict__ att) {
    int pix = blockIdx.x * blockDim.x + threadIdx.x;
    if (pix >= HW) return;
    int h = pix / WDIM, w = pix - h * WDIM;
    float lg = sp_b[0] + L[pix];
#pragma unroll
    for (int kh = 0; kh < 3; ++kh) {
        int nh = h + kh - 1;
        if (nh < 0 || nh >= HDIM) continue;
#pragma unroll
        for (int kw = 0; kw < 3; ++kw) {
            int nw = w + kw - 1;
            if (nw < 0 || nw >= WDIM) continue;
            int k = kh * 3 + kw;
            lg += cbwg[k] + cbwg[9 + k] * gated[nh * WDIM + nw];
        }
    }
    att[pix] = 1.f / (1.f + expf(-lg));
}

// out[c,h,w] = img[c,h,w] * att[h,w], vectorized float4 (HW % 4 == 0)
__global__ void mul_kernel(const float* __restrict__ img, const float* __restrict__ att,
                           float* __restrict__ out) {
    const size_t n4 = (size_t)CIMG * HW / 4;
    const size_t stride = (size_t)gridDim.x * blockDim.x;
    for (size_t i = (size_t)blockIdx.x * blockDim.x + threadIdx.x; i < n4; i += stride) {
        float4 v = reinterpret_cast<const float4*>(img)[i];
        size_t e = i * 4;
        int pix = (int)(e % HW);  // multiple of 4
        float4 a = reinterpret_cast<const float4*>(att)[pix >> 2];
        v.x *= a.x;
        v.y *= a.y;
        v.z *= a.z;
        v.w *= a.w;
        reinterpret_cast<float4*>(out)[i] = v;
    }
}

extern "C" void kernel_launch(void* const* d_in, const int* in_sizes, int n_in,
                              void* d_out, int out_size, void* d_ws, size_t ws_size,
                              hipStream_t stream) {
    const float* img   = (const float*)d_in[0];
    const float* vf0   = (const float*)d_in[1];
    const float* vc0   = (const float*)d_in[2];
    const int*   g0    = (const int*)d_in[3];
    const float* vf1   = (const float*)d_in[4];
    const float* vc1   = (const float*)d_in[5];
    const int*   g1    = (const int*)d_in[6];
    const float* vf2   = (const float*)d_in[7];
    const float* vc2   = (const float*)d_in[8];
    const int*   g2    = (const int*)d_in[9];
    const float* rd0_w = (const float*)d_in[10];
    const float* rd0_b = (const float*)d_in[11];
    const float* rd1_w = (const float*)d_in[12];
    const float* rd1_b = (const float*)d_in[13];
    const float* rd2_w = (const float*)d_in[14];
    const float* rd2_b = (const float*)d_in[15];
    const float* rd3_w = (const float*)d_in[16];
    const float* rd3_b = (const float*)d_in[17];
    const float* sp_w  = (const float*)d_in[18];
    const float* sp_b  = (const float*)d_in[19];
    float* out = (float*)d_out;

    const int n0 = in_sizes[3] / 2;
    const int n1 = in_sizes[6] / 2;
    const int n2 = in_sizes[9] / 2;

    float* ws    = (float*)d_ws;
    float* L     = ws;             // HW
    float* gated = ws + HW;        // HW
    float* att   = ws + 2 * HW;    // HW
    float* T     = ws + 3 * HW;    // 9*131 (== G2)
    float* G0    = T + 9 * COUT;   // 9*35
    float* G1    = G0 + 9 * 35;    // 9*67
    float* cbwg  = G1 + 9 * 67;    // 18

    hipMemsetAsync(L, 0, HW * sizeof(float), stream);
    precompute_kernel<<<1, 256, 0, stream>>>(rd0_w, rd0_b, rd1_w, rd1_b, rd2_w, rd2_b, sp_w,
                                             T, G0, G1, cbwg);
    gated_kernel<<<(HW + 255) / 256, 256, 0, stream>>>(img, rd3_w, rd3_b, gated);
    scatter_kernel<<<(n0 * 16 + 255) / 256, 256, 0, stream>>>(vf0, vc0, g0, G0, L, n0, 32);
    scatter_kernel<<<(n1 * 16 + 255) / 256, 256, 0, stream>>>(vf1, vc1, g1, G1, L, n1, 64);
    scatter_kernel<<<(n2 * 16 + 255) / 256, 256, 0, stream>>>(vf2, vc2, g2, T, L, n2, 128);
    attention_kernel<<<(HW + 255) / 256, 256, 0, stream>>>(gated, L, cbwg, sp_b, att);
    mul_kernel<<<2048, 256, 0, stream>>>(img, att, out);
}

// Round 3
// 551.700 us; speedup vs baseline: 1.0252x; 1.0252x over previous
//
#include <hip/hip_runtime.h>

#define HDIM 256
#define WDIM 704
#define HW (HDIM * WDIM)
#define HW4 (HW / 4)
#define CIMG 256
#define COUT 131

// ---------------------------------------------------------------------------
// Precompute tiny fused matrices, parallelized over 10 blocks:
//   block 0:    base2[j] = rd2_b[j] + sum_c rd2_w[j,c]*(rd0_b[c]+rd1_b[c])
//               cb[k] = sum_j sp_w[j,k]*base2[j];  wg[k] = sum_j sp_w[j,k]
//   block 1+k:  T[k][c]  = sum_j sp_w[j,k] * rd2_w[j,c]      (9 x 131)
//               G0[k][i] = sum_c T[k][c] * rd0_w[c,i]        (9 x 35)
//               G1[k][i] = sum_c T[k][c] * rd1_w[c,i]        (9 x 67)
// ---------------------------------------------------------------------------
__global__ void precompute_kernel(const float* __restrict__ rd0_w, const float* __restrict__ rd0_b,
                                  const float* __restrict__ rd1_w, const float* __restrict__ rd1_b,
                                  const float* __restrict__ rd2_w, const float* __restrict__ rd2_b,
                                  const float* __restrict__ sp_w,
                                  float* __restrict__ T, float* __restrict__ G0,
                                  float* __restrict__ G1, float* __restrict__ cbwg) {
    int t = threadIdx.x;
    if (blockIdx.x == 0) {
        __shared__ float s_base2[COUT];
        for (int j = t; j < COUT; j += blockDim.x) {
            float acc = rd2_b[j];
            for (int c = 0; c < COUT; ++c) acc += rd2_w[j * COUT + c] * (rd0_b[c] + rd1_b[c]);
            s_base2[j] = acc;
        }
        __syncthreads();
        if (t < 9) {
            float acc = 0.f, accw = 0.f;
            for (int j = 0; j < COUT; ++j) {
                acc += sp_w[j * 9 + t] * s_base2[j];
                accw += sp_w[j * 9 + t];
            }
            cbwg[t] = acc;
            cbwg[9 + t] = accw;
        }
    } else {
        int k = blockIdx.x - 1;
        __shared__ float s_Tk[COUT];
        for (int c = t; c < COUT; c += blockDim.x) {
            float acc = 0.f;
            for (int j = 0; j < COUT; ++j) acc += sp_w[j * 9 + k] * rd2_w[j * COUT + c];
            s_Tk[c] = acc;
            T[k * COUT + c] = acc;
        }
        __syncthreads();
        for (int i = t; i < 35; i += blockDim.x) {
            float acc = 0.f;
            for (int c = 0; c < COUT; ++c) acc += s_Tk[c] * rd0_w[c * 35 + i];
            G0[k * 35 + i] = acc;
        }
        for (int i = t; i < 67; i += blockDim.x) {
            float acc = 0.f;
            for (int c = 0; c < COUT; ++c) acc += s_Tk[c] * rd1_w[c * 67 + i];
            G1[k * 67 + i] = acc;
        }
    }
}

// gated(pix) = rd3_b + sum_c rd3_w[c] * img[c,pix]   (float4 over pixels)
__global__ void gated_kernel(const float4* __restrict__ img4, const float* __restrict__ rd3_w,
                             const float* __restrict__ rd3_b, float4* __restrict__ gated4) {
    int i = blockIdx.x * blockDim.x + threadIdx.x;
    if (i >= HW4) return;
    float b = rd3_b[0];
    float4 g = {b, b, b, b};
#pragma unroll 8
    for (int c = 0; c < CIMG; ++c) {
        float w = rd3_w[c];
        float4 v = img4[(size_t)c * HW4 + i];
        g.x += w * v.x;
        g.y += w * v.y;
        g.z += w * v.z;
        g.w += w * v.w;
    }
    gated4[i] = g;
}

// Per point: t[k] = G[k,:] . [feat;coord]; store-add into tap plane R[k][cell].
// Cells are unique within one level, and the three level kernels are
// stream-ordered, so plain read-modify-write is race-free (no atomics).
__global__ void scatter_kernel(const float* __restrict__ feat, const float* __restrict__ coord,
                               const int* __restrict__ grid, const float* __restrict__ G,
                               float* __restrict__ R, int n, int C) {
    int gid = blockIdx.x * blockDim.x + threadIdx.x;
    int p = gid >> 4;
    int lane = gid & 15;
    if (p >= n) return;
    int D = C + 3;
    float part[9];
#pragma unroll
    for (int k = 0; k < 9; ++k) part[k] = 0.f;
    for (int i = lane; i < D; i += 16) {
        float x = (i < C) ? feat[(size_t)p * C + i] : coord[(size_t)p * 3 + (i - C)];
#pragma unroll
        for (int k = 0; k < 9; ++k) part[k] += G[k * D + i] * x;
    }
#pragma unroll
    for (int k = 0; k < 9; ++k) {
        float v = part[k];
        v += __shfl_xor(v, 1);
        v += __shfl_xor(v, 2);
        v += __shfl_xor(v, 4);
        v += __shfl_xor(v, 8);
        part[k] = v;
    }
    if (lane < 9) {
        int cx = grid[2 * p], cy = grid[2 * p + 1];
        int cell = cy * WDIM + cx;
        R[lane * HW + cell] += part[lane];
    }
}

// logit(p) = sp_b + sum over in-bounds taps k of
//            ( cb[k] + wg[k]*gated[n_k] + R[k][n_k] ),  n_k = p + (kh-1, kw-1)
__global__ void attention_kernel(const float* __restrict__ gated, const float* __restrict__ R,
                                 const float* __restrict__ cbwg, const float* __restrict__ sp_b,
                                 float* __restrict__ att) {
    int pix = blockIdx.x * blockDim.x + threadIdx.x;
    if (pix >= HW) return;
    int h = pix / WDIM, w = pix - h * WDIM;
    float lg = sp_b[0];
#pragma unroll
    for (int kh = 0; kh < 3; ++kh) {
        int nh = h + kh - 1;
        if (nh < 0 || nh >= HDIM) continue;
#pragma unroll
        for (int kw = 0; kw < 3; ++kw) {
            int nw = w + kw - 1;
            if (nw < 0 || nw >= WDIM) continue;
            int k = kh * 3 + kw;
            int n = nh * WDIM + nw;
            lg += cbwg[k] + cbwg[9 + k] * gated[n] + R[k * HW + n];
        }
    }
    att[pix] = 1.f / (1.f + expf(-lg));
}

// out[c,pix] = img[c,pix] * att[pix]; 8 channels per block, float4 pixels.
__global__ void mul_kernel(const float4* __restrict__ img4, const float4* __restrict__ att4,
                           float4* __restrict__ out4) {
    int i = blockIdx.x * blockDim.x + threadIdx.x;
    if (i >= HW4) return;
    float4 a = att4[i];
#pragma unroll
    for (int cc = 0; cc < 8; ++cc) {
        size_t idx = (size_t)(blockIdx.y * 8 + cc) * HW4 + i;
        float4 v = img4[idx];
        v.x *= a.x;
        v.y *= a.y;
        v.z *= a.z;
        v.w *= a.w;
        out4[idx] = v;
    }
}

extern "C" void kernel_launch(void* const* d_in, const int* in_sizes, int n_in,
                              void* d_out, int out_size, void* d_ws, size_t ws_size,
                              hipStream_t stream) {
    const float* img   = (const float*)d_in[0];
    const float* vf0   = (const float*)d_in[1];
    const float* vc0   = (const float*)d_in[2];
    const int*   g0    = (const int*)d_in[3];
    const float* vf1   = (const float*)d_in[4];
    const float* vc1   = (const float*)d_in[5];
    const int*   g1    = (const int*)d_in[6];
    const float* vf2   = (const float*)d_in[7];
    const float* vc2   = (const float*)d_in[8];
    const int*   g2    = (const int*)d_in[9];
    const float* rd0_w = (const float*)d_in[10];
    const float* rd0_b = (const float*)d_in[11];
    const float* rd1_w = (const float*)d_in[12];
    const float* rd1_b = (const float*)d_in[13];
    const float* rd2_w = (const float*)d_in[14];
    const float* rd2_b = (const float*)d_in[15];
    const float* rd3_w = (const float*)d_in[16];
    const float* rd3_b = (const float*)d_in[17];
    const float* sp_w  = (const float*)d_in[18];
    const float* sp_b  = (const float*)d_in[19];
    float* out = (float*)d_out;

    const int n0 = in_sizes[3] / 2;
    const int n1 = in_sizes[6] / 2;
    const int n2 = in_sizes[9] / 2;

    float* ws    = (float*)d_ws;
    float* R     = ws;                  // 9*HW tap planes
    float* gated = R + 9 * HW;          // HW
    float* att   = gated + HW;          // HW
    float* T     = att + HW;            // 9*131
    float* G0    = T + 9 * COUT;        // 9*35
    float* G1    = G0 + 9 * 35;         // 9*67
    float* cbwg  = G1 + 9 * 67;         // 18

    hipMemsetAsync(R, 0, (size_t)9 * HW * sizeof(float), stream);
    precompute_kernel<<<10, 256, 0, stream>>>(rd0_w, rd0_b, rd1_w, rd1_b, rd2_w, rd2_b, sp_w,
                                              T, G0, G1, cbwg);
    gated_kernel<<<(HW4 + 255) / 256, 256, 0, stream>>>(
        (const float4*)img, rd3_w, rd3_b, (float4*)gated);
    scatter_kernel<<<(n0 * 16 + 255) / 256, 256, 0, stream>>>(vf0, vc0, g0, G0, R, n0, 32);
    scatter_kernel<<<(n1 * 16 + 255) / 256, 256, 0, stream>>>(vf1, vc1, g1, G1, R, n1, 64);
    scatter_kernel<<<(n2 * 16 + 255) / 256, 256, 0, stream>>>(vf2, vc2, g2, T, R, n2, 128);
    attention_kernel<<<(HW + 255) / 256, 256, 0, stream>>>(gated, R, cbwg, sp_b, att);
    dim3 mgrid((HW4 + 255) / 256, CIMG / 8);
    mul_kernel<<<mgrid, 256, 0, stream>>>((const float4*)img, (const float4*)att, (float4*)out);
}